// Round 1
// baseline (120.289 us; speedup 1.0000x reference)
//
#include <hip/hip_runtime.h>

// SparseUnpool2d: out[b,c,h,w] = (pooled[b,c,h/2,w/2] > 0.5f) ? sparse[b,c,h,w] : 0
// Shapes fixed by setup_inputs(): B=16, C=64, PH=PW=128, S=2, H=W=256.
// Pure memory-bound: ~576 MiB traffic/call -> roofline ~96us @ 6.3 TB/s.

#define B_  16
#define C_  64
#define PH_ 128
#define PW_ 128
#define H_  256
#define W_  256

__global__ __launch_bounds__(256) void sparse_unpool_kernel(
    const float* __restrict__ pooled,   // [B,C,PH,PW]
    const float* __restrict__ sparse,   // [B,C,H,W]
    float* __restrict__ out,            // [B,C,H,W]
    long long n4)                       // total float4 elements = B*C*H*W/4
{
    const long long stride = (long long)gridDim.x * blockDim.x;
    for (long long i4 = (long long)blockIdx.x * blockDim.x + threadIdx.x;
         i4 < n4; i4 += stride) {
        // i4 indexes float4 chunks along W. W=256 -> 64 chunks/row.
        const long long row = i4 >> 6;          // output row index = bc*H + h
        const int w4  = (int)(i4 & 63);         // which float4 within the row
        const int h   = (int)(row & (H_ - 1));  // h in [0,256)
        const long long bc = row >> 8;          // b*C + c

        // pooled offset: bc*PH*PW + (h>>1)*PW + (w0>>1), w0 = w4*4 -> pw0 = w4*2 (even)
        const long long poff = bc * (PH_ * PW_) + (long long)(h >> 1) * PW_ + (w4 << 1);
        const float2 p = *reinterpret_cast<const float2*>(pooled + poff);

        const float4 s = *reinterpret_cast<const float4*>(sparse + (i4 << 2));

        float4 o;
        o.x = (p.x > 0.5f) ? s.x : 0.0f;
        o.y = (p.x > 0.5f) ? s.y : 0.0f;
        o.z = (p.y > 0.5f) ? s.z : 0.0f;
        o.w = (p.y > 0.5f) ? s.w : 0.0f;
        *reinterpret_cast<float4*>(out + (i4 << 2)) = o;
    }
}

extern "C" void kernel_launch(void* const* d_in, const int* in_sizes, int n_in,
                              void* d_out, int out_size, void* d_ws, size_t ws_size,
                              hipStream_t stream) {
    const float* pooled = (const float*)d_in[0];
    const float* sparse = (const float*)d_in[1];
    float* out = (float*)d_out;

    const long long n4 = (long long)out_size / 4;   // 16,777,216
    const int block = 256;
    const int grid = 2048;  // ~8 blocks/CU on 256 CUs; grid-stride covers the rest
    sparse_unpool_kernel<<<grid, block, 0, stream>>>(pooled, sparse, out, n4);
}